// Round 4
// baseline (1562.144 us; speedup 1.0000x reference)
//
#include <hip/hip_runtime.h>
#include <hip/hip_bf16.h>

#define Bb 8
#define Tt 600
#define Cc 8
#define Ff 257
#define TAPS 5
#define DELAY 3
#define KC 40            // TAPS*C
#define NC 48            // KC + C (R columns | P columns)
#define RPW 52           // RP row stride (float2): 104 dwords % 32 = 8 -> 2-way max (free)
#define TQ 593           // T - DELAY - TAPS + 1
#define TP 602           // Y LDS row stride (float2)
#define EPSF 1e-10f
#define NTOT (Bb*Tt*Cc*Ff)   // 9,868,800

__device__ __forceinline__ float2 cmul2(float2 a, float2 b) {
  return make_float2(a.x*b.x - a.y*b.y, a.x*b.y + a.y*b.x);
}

// acc += conj(a)*b with a pre-scaled: (ax,ay) = (w*y.x, w*y.y)
#define CMAC(acc, ax, ay, b)                    \
  acc.x = fmaf(ax, b.x, acc.x);                 \
  acc.x = fmaf(ay, b.y, acc.x);                 \
  acc.y = fmaf(ax, b.y, acc.y);                 \
  acc.y = fmaf(-(ay), b.x, acc.y);

// (B,T,C,F) re/im planes -> (B,F,C,T) interleaved float2
__global__ __launch_bounds__(256) void k_tin(const float* __restrict__ in_re,
                                             const float* __restrict__ in_im,
                                             float2* __restrict__ Yt) {
  __shared__ float2 tile[32][33];
  int f0 = blockIdx.x * 32, t0 = blockIdx.y * 32;
  int b = blockIdx.z >> 3, c = blockIdx.z & 7;
  int tx = threadIdx.x & 31, ty = threadIdx.x >> 5;
#pragma unroll
  for (int ii = 0; ii < 4; ++ii) {
    int t = t0 + ty + 8 * ii, f = f0 + tx;
    if (t < Tt && f < Ff) {
      size_t idx = (((size_t)b * Tt + t) * Cc + c) * Ff + f;
      tile[ty + 8 * ii][tx] = make_float2(in_re[idx], in_im[idx]);
    }
  }
  __syncthreads();
#pragma unroll
  for (int ii = 0; ii < 4; ++ii) {
    int f = f0 + ty + 8 * ii, t = t0 + tx;
    if (f < Ff && t < Tt) {
      size_t o = (((size_t)b * Ff + f) * Cc + c) * Tt + t;
      Yt[o] = tile[tx][ty + 8 * ii];
    }
  }
}

// Unrolled accumulation body; u is a literal 0..4 so all %5 indices fold.
#define ABODY(u) do {                                                     \
  float2 ynd = Yd[tb + (u) + 4];                                          \
  float2 yne = Ye[tb + (u) + 4];                                          \
  float2 yep = Ye[tb + (u) + 7];                                          \
  float w = wl[tb + (u) + 7];                                             \
  wd[((u)+4)%5] = ynd; we[((u)+4)%5] = yne;                               \
  float ax[5], ay[5];                                                     \
  _Pragma("unroll")                                                       \
  for (int k = 0; k < 5; ++k) {                                           \
    float2 yr = wd[((u)+4-k)%5]; ax[k] = w*yr.x; ay[k] = w*yr.y;          \
  }                                                                       \
  _Pragma("unroll")                                                       \
  for (int l = 0; l < 5; ++l) {                                           \
    float2 yc = we[((u)+4-l)%5];                                          \
    _Pragma("unroll")                                                     \
    for (int k = 0; k < 5; ++k) { CMAC(rac[k][l], ax[k], ay[k], yc); }    \
  }                                                                       \
  _Pragma("unroll")                                                       \
  for (int k = 0; k < 5; ++k) { CMAC(pac[k], ax[k], ay[k], yep); }        \
} while (0)

// One block (512 thr) per (b,f): full 2-iteration WPE.
// Accumulation: 8 t-split groups of 64, thread=(d,e) owns 5x5 R-tile + 5 P
// via register sliding windows; atomic LDS merge; deferred-scale GJ solve.
// LDS caps us at 2 blocks/CU (16 waves = 4 waves/SIMD), so allow 128 VGPRs.
__global__ __attribute__((amdgpu_waves_per_eu(4)))
__launch_bounds__(512) void k_wpe(const float2* __restrict__ Yt,
                                  float2* __restrict__ enh,
                                  const float* __restrict__ in_re,
                                  const float* __restrict__ in_im,
                                  const int* __restrict__ ilens,
                                  float* __restrict__ out_re,
                                  float* __restrict__ out_im,
                                  int load_direct, int store_direct) {
  __shared__ float2 Yl[Cc][TP];        // 8 x 602 complex = 38528 B
  __shared__ float2 RP[KC][RPW];       // [R | P] 40 x 52      = 16640 B
  __shared__ float wl[Tt];             // 2400 B   -> total 57568 B

  int bf = blockIdx.x;
  int b = bf / Ff, f = bf % Ff;
  int tid = threadIdx.x;               // 0..511
  int group = tid >> 6;                // t-split group (wave)
  int lane = tid & 63;
  int d = lane & 7;                    // row channel
  int e = lane >> 3;                   // col channel

  // ---- stage Y into LDS
  if (!load_direct) {
    const float4* Yg = (const float4*)(Yt + (size_t)bf * (Cc * Tt));
    for (int i = tid; i < Cc * Tt / 2; i += 512) {
      float4 v = Yg[i];
      int c = i / (Tt / 2), t2 = (i % (Tt / 2)) * 2;
      *(float4*)&Yl[c][t2] = v;        // 16B aligned: 602*c + t2 even
    }
  } else {
    for (int i = tid; i < Cc * Tt; i += 512) {
      int c = i / Tt, t = i % Tt;
      size_t idx = (((size_t)b * Tt + t) * Cc + c) * Ff + f;
      Yl[c][t] = make_float2(in_re[idx], in_im[idx]);
    }
  }
  __syncthreads();

  const float2* Yd = &Yl[d][0];
  const float2* Ye = &Yl[e][0];

  int tA = (TQ * group) >> 3;
  int tB = (TQ * (group + 1)) >> 3;
  int si = tid >> 3;                   // solve row
  int sk = tid & 7;                    // solve col phase

  for (int iter = 0; iter < 3; ++iter) {
    // ---- weights (iter 0 from Y; iter 1 from enhanced_0); iter 2: store result
    if (iter == 0) {
      for (int t = tid; t < Tt; t += 512) {
        float s = 0.f;
#pragma unroll
        for (int c = 0; c < Cc; ++c) { float2 y = Yl[c][t]; s += y.x*y.x + y.y*y.y; }
        wl[t] = 1.0f / fmaxf(s * 0.125f, EPSF);
      }
    } else {
      for (int t = tid; t < Tt; t += 512) {
        float2 acc[Cc];
#pragma unroll
        for (int ee = 0; ee < Cc; ++ee) acc[ee] = Yl[ee][t];
        for (int p = 0; p < TAPS; ++p) {
          int ts = t - DELAY - p;
          if (ts < 0) break;   // zero-padded region
#pragma unroll
          for (int dd = 0; dd < Cc; ++dd) {
            float2 u = Yl[dd][ts];
            int j = p * Cc + dd;
#pragma unroll
            for (int ee = 0; ee < Cc; ++ee) {
              float2 g = RP[j][KC + ee];   // filter X[j][e] from the solve
              acc[ee].x -= g.x*u.x - g.y*u.y;
              acc[ee].y -= g.x*u.y + g.y*u.x;
            }
          }
        }
        if (iter == 1) {
          float s = 0.f;
#pragma unroll
          for (int ee = 0; ee < Cc; ++ee) s += acc[ee].x*acc[ee].x + acc[ee].y*acc[ee].y;
          wl[t] = 1.0f / fmaxf(s * 0.125f, EPSF);
        } else {
          if (!store_direct) {
            float2* Eg = enh + (size_t)bf * (Cc * Tt);
#pragma unroll
            for (int ee = 0; ee < Cc; ++ee) Eg[ee * Tt + t] = acc[ee];
          } else {
            int il = ilens[b];
            bool live = (t < il);
#pragma unroll
            for (int ee = 0; ee < Cc; ++ee) {
              float2 v = live ? acc[ee] : make_float2(0.f, 0.f);
              size_t idx = (((size_t)b * Tt + t) * Cc + ee) * Ff + f;
              out_re[idx] = v.x;
              out_im[idx] = v.y;
            }
          }
        }
      }
    }
    if (iter == 2) break;
    __syncthreads();

    // ---- zero RP (atomic-merge target)
    {
      float2* RPf = &RP[0][0];
      for (int i = tid; i < KC * RPW; i += 512) RPf[i] = make_float2(0.f, 0.f);
    }
    __syncthreads();

    // ---- accumulate [R | P]: per-thread 5x5+5 tile, register sliding windows
    float2 rac[5][5], pac[5];
#pragma unroll
    for (int k = 0; k < 5; ++k) {
#pragma unroll
      for (int l = 0; l < 5; ++l) rac[k][l] = make_float2(0.f, 0.f);
      pac[k] = make_float2(0.f, 0.f);
    }

    float2 wd[5], we[5];
#pragma unroll
    for (int i = 0; i < 4; ++i) { wd[i] = Yd[tA + i]; we[i] = Ye[tA + i]; }

    int tb = tA;
    for (; tb + 5 <= tB; tb += 5) {
      ABODY(0); ABODY(1); ABODY(2); ABODY(3); ABODY(4);
    }
    for (int t = tb; t < tB; ++t) {    // tail (<=4 iters): read fresh
      float2 yep = Ye[t + 7];
      float w = wl[t + 7];
      float ax[5], ay[5];
#pragma unroll
      for (int k = 0; k < 5; ++k) {
        float2 yr = Yd[t + 4 - k]; ax[k] = w*yr.x; ay[k] = w*yr.y;
      }
#pragma unroll
      for (int l = 0; l < 5; ++l) {
        float2 yc = Ye[t + 4 - l];
#pragma unroll
        for (int k = 0; k < 5; ++k) { CMAC(rac[k][l], ax[k], ay[k], yc); }
      }
#pragma unroll
      for (int k = 0; k < 5; ++k) { CMAC(pac[k], ax[k], ay[k], yep); }
    }

    // ---- merge 8 group partials: LDS float atomics (single barrier)
#pragma unroll
    for (int k = 0; k < 5; ++k) {
#pragma unroll
      for (int l = 0; l < 5; ++l) {
        atomicAdd(&RP[k * 8 + d][l * 8 + e].x, rac[k][l].x);
        atomicAdd(&RP[k * 8 + d][l * 8 + e].y, rac[k][l].y);
      }
      atomicAdd(&RP[k * 8 + d][KC + e].x, pac[k].x);
      atomicAdd(&RP[k * 8 + d][KC + e].y, pac[k].y);
    }
    if (tid < KC) atomicAdd(&RP[tid][tid].x, EPSF);   // regularize
    __syncthreads();

    // ---- Gauss-Jordan with deferred pivot scaling: one barrier per pivot.
    // Row i (i != j): RP[i][k>j] -= (RP[i][j]/RP[j][j]) * RP[j][k]. Row j
    // stays unscaled; X recovered at the end by dividing cols 40..47 by diag.
    for (int j = 0; j < KC; ++j) {
      if (si < KC && si != j) {
        float2 pv = RP[j][j];
        float idn = 1.0f / (pv.x * pv.x + pv.y * pv.y);
        float2 ip = make_float2(pv.x * idn, -pv.y * idn);
        float2 lij = cmul2(RP[si][j], ip);
        for (int k = j + 1 + sk; k < NC; k += 8) {
          float2 s = cmul2(lij, RP[j][k]);
          RP[si][k].x -= s.x;
          RP[si][k].y -= s.y;
        }
      }
      __syncthreads();
    }
    if (tid < KC * Cc) {
      int j = tid >> 3, ee = tid & 7;
      float2 pv = RP[j][j];
      float idn = 1.0f / (pv.x * pv.x + pv.y * pv.y);
      float2 ip = make_float2(pv.x * idn, -pv.y * idn);
      RP[j][KC + ee] = cmul2(RP[j][KC + ee], ip);
    }
    __syncthreads();
  }
}

// (B,F,C,T) float2 -> masked (B,T,C,F) re/im planes
__global__ __launch_bounds__(256) void k_tout(const float2* __restrict__ enh,
                                              const int* __restrict__ ilens,
                                              float* __restrict__ out_re,
                                              float* __restrict__ out_im) {
  __shared__ float2 tile[32][33];
  int t0 = blockIdx.x * 32, f0 = blockIdx.y * 32;
  int b = blockIdx.z >> 3, c = blockIdx.z & 7;
  int tx = threadIdx.x & 31, ty = threadIdx.x >> 5;
#pragma unroll
  for (int ii = 0; ii < 4; ++ii) {
    int f = f0 + ty + 8 * ii, t = t0 + tx;
    if (f < Ff && t < Tt)
      tile[ty + 8 * ii][tx] = enh[(((size_t)b * Ff + f) * Cc + c) * Tt + t];
  }
  __syncthreads();
  int il = ilens[b];
#pragma unroll
  for (int ii = 0; ii < 4; ++ii) {
    int t = t0 + ty + 8 * ii, f = f0 + tx;
    if (t < Tt && f < Ff) {
      float2 v = tile[tx][ty + 8 * ii];
      if (t >= il) v = make_float2(0.f, 0.f);
      size_t idx = (((size_t)b * Tt + t) * Cc + c) * Ff + f;
      out_re[idx] = v.x;
      out_im[idx] = v.y;
    }
  }
}

extern "C" void kernel_launch(void* const* d_in, const int* in_sizes, int n_in,
                              void* d_out, int out_size, void* d_ws, size_t ws_size,
                              hipStream_t stream) {
  const float* in_re = (const float*)d_in[0];
  const float* in_im = (const float*)d_in[1];
  const int* ilens = (const int*)d_in[2];
  float* out_re = (float*)d_out;
  float* out_im = out_re + NTOT;

  size_t ybytes = (size_t)Bb * Ff * Cc * Tt * sizeof(float2);  // 78,950,400 B
  int have_yt  = ws_size >= ybytes;
  int have_enh = ws_size >= 2 * ybytes;
  float2* Yt  = (float2*)d_ws;
  float2* enh = (float2*)((char*)d_ws + ybytes);

  if (have_yt) {
    dim3 g((Ff + 31) / 32, (Tt + 31) / 32, Bb * Cc);
    k_tin<<<g, dim3(256), 0, stream>>>(in_re, in_im, Yt);
  }
  {
    dim3 g(Bb * Ff);
    k_wpe<<<g, dim3(512), 0, stream>>>(Yt, enh, in_re, in_im, ilens,
                                       out_re, out_im,
                                       have_yt ? 0 : 1, have_enh ? 0 : 1);
  }
  if (have_enh) {
    dim3 g((Tt + 31) / 32, (Ff + 31) / 32, Bb * Cc);
    k_tout<<<g, dim3(256), 0, stream>>>(enh, ilens, out_re, out_im);
  }
}

// Round 5
// 1468.541 us; speedup vs baseline: 1.0637x; 1.0637x over previous
//
#include <hip/hip_runtime.h>
#include <hip/hip_bf16.h>

#define Bb 8
#define Tt 600
#define Cc 8
#define Ff 257
#define TAPS 5
#define DELAY 3
#define KC 40            // TAPS*C
#define NC 48            // KC + C (R columns | P columns)
#define RPW 52           // RP row stride (float2)
#define TQ 593           // T - DELAY - TAPS + 1
#define TP 602           // Y LDS row stride (float2)
#define EPSF 1e-10f
#define NTOT (Bb*Tt*Cc*Ff)   // 9,868,800

__device__ __forceinline__ float2 cmul2(float2 a, float2 b) {
  return make_float2(a.x*b.x - a.y*b.y, a.x*b.y + a.y*b.x);
}

// acc += conj((ax,ay)) * b
#define CMAC(acc, ax, ay, b)                    \
  acc.x = fmaf(ax, b.x, acc.x);                 \
  acc.x = fmaf(ay, b.y, acc.x);                 \
  acc.y = fmaf(ax, b.y, acc.y);                 \
  acc.y = fmaf(-(ay), b.x, acc.y);

// (B,T,C,F) re/im planes -> (B,F,C,T) interleaved float2
__global__ __launch_bounds__(256) void k_tin(const float* __restrict__ in_re,
                                             const float* __restrict__ in_im,
                                             float2* __restrict__ Yt) {
  __shared__ float2 tile[32][33];
  int f0 = blockIdx.x * 32, t0 = blockIdx.y * 32;
  int b = blockIdx.z >> 3, c = blockIdx.z & 7;
  int tx = threadIdx.x & 31, ty = threadIdx.x >> 5;
#pragma unroll
  for (int ii = 0; ii < 4; ++ii) {
    int t = t0 + ty + 8 * ii, f = f0 + tx;
    if (t < Tt && f < Ff) {
      size_t idx = (((size_t)b * Tt + t) * Cc + c) * Ff + f;
      tile[ty + 8 * ii][tx] = make_float2(in_re[idx], in_im[idx]);
    }
  }
  __syncthreads();
#pragma unroll
  for (int ii = 0; ii < 4; ++ii) {
    int f = f0 + ty + 8 * ii, t = t0 + tx;
    if (f < Ff && t < Tt) {
      size_t o = (((size_t)b * Ff + f) * Cc + c) * Tt + t;
      Yt[o] = tile[tx][ty + 8 * ii];
    }
  }
}

// half 0: columns l = 0,1,2 (cols Ye[t+4], Ye[t+3], Ye[t+2])
#define ABODY0(u) do {                                                    \
  int t = tb + (u);                                                       \
  float2 ynd = Yd[t + 4];                                                 \
  wd[((u)+4)%5] = ynd;                                                    \
  float w = wl[t + 7];                                                    \
  float2 c0 = Ye[t + 4], c1 = Ye[t + 3], c2 = Ye[t + 2];                  \
  float2 s0 = make_float2(w*c0.x, w*c0.y);                                \
  float2 s1 = make_float2(w*c1.x, w*c1.y);                                \
  float2 s2 = make_float2(w*c2.x, w*c2.y);                                \
  _Pragma("unroll")                                                       \
  for (int k = 0; k < 5; ++k) {                                           \
    float2 yr = wd[((u)+4-k)%5];                                          \
    CMAC(rac[k][0], yr.x, yr.y, s0);                                      \
    CMAC(rac[k][1], yr.x, yr.y, s1);                                      \
    CMAC(rac[k][2], yr.x, yr.y, s2);                                      \
  }                                                                       \
} while (0)

// half 1: columns l = 3,4 (Ye[t+1], Ye[t]) + P column (Ye[t+7])
#define ABODY1(u) do {                                                    \
  int t = tb + (u);                                                       \
  float2 ynd = Yd[t + 4];                                                 \
  wd[((u)+4)%5] = ynd;                                                    \
  float w = wl[t + 7];                                                    \
  float2 c3 = Ye[t + 1], c4 = Ye[t], cp = Ye[t + 7];                      \
  float2 s3 = make_float2(w*c3.x, w*c3.y);                                \
  float2 s4 = make_float2(w*c4.x, w*c4.y);                                \
  float2 sp = make_float2(w*cp.x, w*cp.y);                                \
  _Pragma("unroll")                                                       \
  for (int k = 0; k < 5; ++k) {                                           \
    float2 yr = wd[((u)+4-k)%5];                                          \
    CMAC(rac[k][0], yr.x, yr.y, s3);                                      \
    CMAC(rac[k][1], yr.x, yr.y, s4);                                      \
    CMAC(pac[k],    yr.x, yr.y, sp);                                      \
  }                                                                       \
} while (0)

// One block (512 thr) per (b,f): full 2-iteration WPE.
// Accumulation: 4 t-split groups x 2 l-split waves x 64 (d,e) threads.
// Per-thread: 15 complex accumulators + 5-deep row window -> fits 64 VGPRs.
__global__ __launch_bounds__(512) void k_wpe(const float2* __restrict__ Yt,
                                             float2* __restrict__ enh,
                                             const float* __restrict__ in_re,
                                             const float* __restrict__ in_im,
                                             const int* __restrict__ ilens,
                                             float* __restrict__ out_re,
                                             float* __restrict__ out_im,
                                             int load_direct, int store_direct) {
  __shared__ float2 Yl[Cc][TP];        // 8 x 602 complex = 38528 B
  __shared__ float2 RP[KC][RPW];       // [R | P] 40 x 52  = 16640 B
  __shared__ float wl[Tt];             // 2400 B   -> total 57568 B

  int bf = blockIdx.x;
  int b = bf / Ff, f = bf % Ff;
  int tid = threadIdx.x;               // 0..511
  int group = tid >> 7;                // t-split quarter (2 waves)
  int half = (tid >> 6) & 1;           // l-split (wave-uniform)
  int lane = tid & 63;
  int d = lane & 7;                    // row channel
  int e = lane >> 3;                   // col channel

  // ---- stage Y into LDS
  if (!load_direct) {
    const float4* Yg = (const float4*)(Yt + (size_t)bf * (Cc * Tt));
    for (int i = tid; i < Cc * Tt / 2; i += 512) {
      float4 v = Yg[i];
      int c = i / (Tt / 2), t2 = (i % (Tt / 2)) * 2;
      *(float4*)&Yl[c][t2] = v;        // 16B aligned: 602*c + t2 even
    }
  } else {
    for (int i = tid; i < Cc * Tt; i += 512) {
      int c = i / Tt, t = i % Tt;
      size_t idx = (((size_t)b * Tt + t) * Cc + c) * Ff + f;
      Yl[c][t] = make_float2(in_re[idx], in_im[idx]);
    }
  }
  __syncthreads();

  const float2* Yd = &Yl[d][0];
  const float2* Ye = &Yl[e][0];

  int tA = (TQ * group) >> 2;
  int tB = (TQ * (group + 1)) >> 2;
  int si = tid >> 3;                   // solve row
  int sk = tid & 7;                    // solve col phase

  for (int iter = 0; iter < 3; ++iter) {
    // ---- weights (iter 0 from Y; iter 1 from enhanced_0); iter 2: store result
    if (iter == 0) {
      for (int t = tid; t < Tt; t += 512) {
        float s = 0.f;
#pragma unroll
        for (int c = 0; c < Cc; ++c) { float2 y = Yl[c][t]; s += y.x*y.x + y.y*y.y; }
        wl[t] = 1.0f / fmaxf(s * 0.125f, EPSF);
      }
    } else {
      for (int t = tid; t < Tt; t += 512) {
        float2 acc[Cc];
#pragma unroll
        for (int ee = 0; ee < Cc; ++ee) acc[ee] = Yl[ee][t];
        for (int p = 0; p < TAPS; ++p) {
          int ts = t - DELAY - p;
          if (ts < 0) break;   // zero-padded region
#pragma unroll
          for (int dd = 0; dd < Cc; ++dd) {
            float2 u = Yl[dd][ts];
            int j = p * Cc + dd;
#pragma unroll
            for (int ee = 0; ee < Cc; ++ee) {
              float2 g = RP[j][KC + ee];   // filter X[j][e] from the solve
              acc[ee].x -= g.x*u.x - g.y*u.y;
              acc[ee].y -= g.x*u.y + g.y*u.x;
            }
          }
        }
        if (iter == 1) {
          float s = 0.f;
#pragma unroll
          for (int ee = 0; ee < Cc; ++ee) s += acc[ee].x*acc[ee].x + acc[ee].y*acc[ee].y;
          wl[t] = 1.0f / fmaxf(s * 0.125f, EPSF);
        } else {
          if (!store_direct) {
            float2* Eg = enh + (size_t)bf * (Cc * Tt);
#pragma unroll
            for (int ee = 0; ee < Cc; ++ee) Eg[ee * Tt + t] = acc[ee];
          } else {
            int il = ilens[b];
            bool live = (t < il);
#pragma unroll
            for (int ee = 0; ee < Cc; ++ee) {
              float2 v = live ? acc[ee] : make_float2(0.f, 0.f);
              size_t idx = (((size_t)b * Tt + t) * Cc + ee) * Ff + f;
              out_re[idx] = v.x;
              out_im[idx] = v.y;
            }
          }
        }
      }
    }
    if (iter == 2) break;
    __syncthreads();

    // ---- zero RP (atomic-merge target)
    {
      float2* RPf = &RP[0][0];
      for (int i = tid; i < KC * RPW; i += 512) RPf[i] = make_float2(0.f, 0.f);
    }
    __syncthreads();

    // ---- accumulate [R | P]: per-thread 5x3 (or 5x2+P) tile, row window
    if (half == 0) {
      float2 rac[5][3];
#pragma unroll
      for (int k = 0; k < 5; ++k)
#pragma unroll
        for (int l = 0; l < 3; ++l) rac[k][l] = make_float2(0.f, 0.f);

      float2 wd[5];
#pragma unroll
      for (int i = 0; i < 4; ++i) wd[i] = Yd[tA + i];

      int tb = tA;
      for (; tb + 5 <= tB; tb += 5) {
        ABODY0(0); ABODY0(1); ABODY0(2); ABODY0(3); ABODY0(4);
      }
      for (int t = tb; t < tB; ++t) {    // tail: fresh reads
        float w = wl[t + 7];
        float2 c0 = Ye[t + 4], c1 = Ye[t + 3], c2 = Ye[t + 2];
        float2 s0 = make_float2(w*c0.x, w*c0.y);
        float2 s1 = make_float2(w*c1.x, w*c1.y);
        float2 s2 = make_float2(w*c2.x, w*c2.y);
#pragma unroll
        for (int k = 0; k < 5; ++k) {
          float2 yr = Yd[t + 4 - k];
          CMAC(rac[k][0], yr.x, yr.y, s0);
          CMAC(rac[k][1], yr.x, yr.y, s1);
          CMAC(rac[k][2], yr.x, yr.y, s2);
        }
      }
#pragma unroll
      for (int k = 0; k < 5; ++k)
#pragma unroll
        for (int l = 0; l < 3; ++l) {
          atomicAdd(&RP[k * 8 + d][l * 8 + e].x, rac[k][l].x);
          atomicAdd(&RP[k * 8 + d][l * 8 + e].y, rac[k][l].y);
        }
    } else {
      float2 rac[5][2], pac[5];
#pragma unroll
      for (int k = 0; k < 5; ++k) {
        rac[k][0] = make_float2(0.f, 0.f);
        rac[k][1] = make_float2(0.f, 0.f);
        pac[k]    = make_float2(0.f, 0.f);
      }

      float2 wd[5];
#pragma unroll
      for (int i = 0; i < 4; ++i) wd[i] = Yd[tA + i];

      int tb = tA;
      for (; tb + 5 <= tB; tb += 5) {
        ABODY1(0); ABODY1(1); ABODY1(2); ABODY1(3); ABODY1(4);
      }
      for (int t = tb; t < tB; ++t) {    // tail: fresh reads
        float w = wl[t + 7];
        float2 c3 = Ye[t + 1], c4 = Ye[t], cp = Ye[t + 7];
        float2 s3 = make_float2(w*c3.x, w*c3.y);
        float2 s4 = make_float2(w*c4.x, w*c4.y);
        float2 sp = make_float2(w*cp.x, w*cp.y);
#pragma unroll
        for (int k = 0; k < 5; ++k) {
          float2 yr = Yd[t + 4 - k];
          CMAC(rac[k][0], yr.x, yr.y, s3);
          CMAC(rac[k][1], yr.x, yr.y, s4);
          CMAC(pac[k],    yr.x, yr.y, sp);
        }
      }
#pragma unroll
      for (int k = 0; k < 5; ++k) {
        atomicAdd(&RP[k * 8 + d][3 * 8 + e].x, rac[k][0].x);
        atomicAdd(&RP[k * 8 + d][3 * 8 + e].y, rac[k][0].y);
        atomicAdd(&RP[k * 8 + d][4 * 8 + e].x, rac[k][1].x);
        atomicAdd(&RP[k * 8 + d][4 * 8 + e].y, rac[k][1].y);
        atomicAdd(&RP[k * 8 + d][KC + e].x, pac[k].x);
        atomicAdd(&RP[k * 8 + d][KC + e].y, pac[k].y);
      }
    }
    if (tid < KC) atomicAdd(&RP[tid][tid].x, EPSF);   // regularize
    __syncthreads();

    // ---- Gauss-Jordan with deferred pivot scaling: one barrier per pivot.
    for (int j = 0; j < KC; ++j) {
      if (si < KC && si != j) {
        float2 pv = RP[j][j];
        float idn = 1.0f / (pv.x * pv.x + pv.y * pv.y);
        float2 ip = make_float2(pv.x * idn, -pv.y * idn);
        float2 lij = cmul2(RP[si][j], ip);
        for (int k = j + 1 + sk; k < NC; k += 8) {
          float2 s = cmul2(lij, RP[j][k]);
          RP[si][k].x -= s.x;
          RP[si][k].y -= s.y;
        }
      }
      __syncthreads();
    }
    if (tid < KC * Cc) {
      int j = tid >> 3, ee = tid & 7;
      float2 pv = RP[j][j];
      float idn = 1.0f / (pv.x * pv.x + pv.y * pv.y);
      float2 ip = make_float2(pv.x * idn, -pv.y * idn);
      RP[j][KC + ee] = cmul2(RP[j][KC + ee], ip);
    }
    __syncthreads();
  }
}

// (B,F,C,T) float2 -> masked (B,T,C,F) re/im planes
__global__ __launch_bounds__(256) void k_tout(const float2* __restrict__ enh,
                                              const int* __restrict__ ilens,
                                              float* __restrict__ out_re,
                                              float* __restrict__ out_im) {
  __shared__ float2 tile[32][33];
  int t0 = blockIdx.x * 32, f0 = blockIdx.y * 32;
  int b = blockIdx.z >> 3, c = blockIdx.z & 7;
  int tx = threadIdx.x & 31, ty = threadIdx.x >> 5;
#pragma unroll
  for (int ii = 0; ii < 4; ++ii) {
    int f = f0 + ty + 8 * ii, t = t0 + tx;
    if (f < Ff && t < Tt)
      tile[ty + 8 * ii][tx] = enh[(((size_t)b * Ff + f) * Cc + c) * Tt + t];
  }
  __syncthreads();
  int il = ilens[b];
#pragma unroll
  for (int ii = 0; ii < 4; ++ii) {
    int t = t0 + ty + 8 * ii, f = f0 + tx;
    if (t < Tt && f < Ff) {
      float2 v = tile[tx][ty + 8 * ii];
      if (t >= il) v = make_float2(0.f, 0.f);
      size_t idx = (((size_t)b * Tt + t) * Cc + c) * Ff + f;
      out_re[idx] = v.x;
      out_im[idx] = v.y;
    }
  }
}

extern "C" void kernel_launch(void* const* d_in, const int* in_sizes, int n_in,
                              void* d_out, int out_size, void* d_ws, size_t ws_size,
                              hipStream_t stream) {
  const float* in_re = (const float*)d_in[0];
  const float* in_im = (const float*)d_in[1];
  const int* ilens = (const int*)d_in[2];
  float* out_re = (float*)d_out;
  float* out_im = out_re + NTOT;

  size_t ybytes = (size_t)Bb * Ff * Cc * Tt * sizeof(float2);  // 78,950,400 B
  int have_yt  = ws_size >= ybytes;
  int have_enh = ws_size >= 2 * ybytes;
  float2* Yt  = (float2*)d_ws;
  float2* enh = (float2*)((char*)d_ws + ybytes);

  if (have_yt) {
    dim3 g((Ff + 31) / 32, (Tt + 31) / 32, Bb * Cc);
    k_tin<<<g, dim3(256), 0, stream>>>(in_re, in_im, Yt);
  }
  {
    dim3 g(Bb * Ff);
    k_wpe<<<g, dim3(512), 0, stream>>>(Yt, enh, in_re, in_im, ilens,
                                       out_re, out_im,
                                       have_yt ? 0 : 1, have_enh ? 0 : 1);
  }
  if (have_enh) {
    dim3 g((Tt + 31) / 32, (Ff + 31) / 32, Bb * Cc);
    k_tout<<<g, dim3(256), 0, stream>>>(enh, ilens, out_re, out_im);
  }
}

// Round 6
// 1449.679 us; speedup vs baseline: 1.0776x; 1.0130x over previous
//
#include <hip/hip_runtime.h>
#include <hip/hip_bf16.h>

#define Bb 8
#define Tt 600
#define Cc 8
#define Ff 257
#define TAPS 5
#define DELAY 3
#define KC 40            // TAPS*C
#define NC 48            // KC + C (R columns | P columns)
#define RPW 52           // RP row stride (float2)
#define TQ 593           // T - DELAY - TAPS + 1
#define TP 602           // Y LDS row stride (float2)
#define EPSF 1e-10f
#define NTOT (Bb*Tt*Cc*Ff)   // 9,868,800

__device__ __forceinline__ float2 cmul2(float2 a, float2 b) {
  return make_float2(a.x*b.x - a.y*b.y, a.x*b.y + a.y*b.x);
}

// acc += conj((ax,ay)) * b
#define CMAC(acc, ax, ay, b)                    \
  acc.x = fmaf(ax, b.x, acc.x);                 \
  acc.x = fmaf(ay, b.y, acc.x);                 \
  acc.y = fmaf(ax, b.y, acc.y);                 \
  acc.y = fmaf(-(ay), b.x, acc.y);

// row yr against this half's three scaled column streams
#define ROWH0(kk, yr)                           \
  CMAC(rac[kk][0], yr.x, yr.y, s0);             \
  CMAC(rac[kk][1], yr.x, yr.y, s1);             \
  CMAC(rac[kk][2], yr.x, yr.y, s2);
#define ROWH1(kk, yr)                           \
  CMAC(rac[kk][0], yr.x, yr.y, s3);             \
  CMAC(rac[kk][1], yr.x, yr.y, s4);             \
  CMAC(pac[kk],    yr.x, yr.y, sp);

// (B,T,C,F) re/im planes -> (B,F,C,T) interleaved float2
__global__ __launch_bounds__(256) void k_tin(const float* __restrict__ in_re,
                                             const float* __restrict__ in_im,
                                             float2* __restrict__ Yt) {
  __shared__ float2 tile[32][33];
  int f0 = blockIdx.x * 32, t0 = blockIdx.y * 32;
  int b = blockIdx.z >> 3, c = blockIdx.z & 7;
  int tx = threadIdx.x & 31, ty = threadIdx.x >> 5;
#pragma unroll
  for (int ii = 0; ii < 4; ++ii) {
    int t = t0 + ty + 8 * ii, f = f0 + tx;
    if (t < Tt && f < Ff) {
      size_t idx = (((size_t)b * Tt + t) * Cc + c) * Ff + f;
      tile[ty + 8 * ii][tx] = make_float2(in_re[idx], in_im[idx]);
    }
  }
  __syncthreads();
#pragma unroll
  for (int ii = 0; ii < 4; ++ii) {
    int f = f0 + ty + 8 * ii, t = t0 + tx;
    if (f < Ff && t < Tt) {
      size_t o = (((size_t)b * Ff + f) * Cc + c) * Tt + t;
      Yt[o] = tile[tx][ty + 8 * ii];
    }
  }
}

// One block (512 thr) per (b,f): full 2-iteration WPE.
// Accumulation: 4 t-split groups x 2 l-split waves x 64 (d,e) threads.
// Per-thread 5x3 (or 5x2+P) complex tile + 5-deep shift-register row window.
// VGPR budget MUST be <=64: 512-thr blocks only co-reside 2/CU at <=64 VGPRs
// (measured R1/R2/R4/R5: 64->40% occ, 80/112->21%).
__global__ __attribute__((amdgpu_num_vgpr(64)))
__launch_bounds__(512) void k_wpe(const float2* __restrict__ Yt,
                                  float2* __restrict__ enh,
                                  const float* __restrict__ in_re,
                                  const float* __restrict__ in_im,
                                  const int* __restrict__ ilens,
                                  float* __restrict__ out_re,
                                  float* __restrict__ out_im,
                                  int load_direct, int store_direct) {
  __shared__ float2 Yl[Cc][TP];        // 8 x 602 complex = 38528 B
  __shared__ float2 RP[KC][RPW];       // [R | P] 40 x 52  = 16640 B
  __shared__ float wl[Tt];             // 2400 B   -> total 57568 B

  int bf = blockIdx.x;
  int b = bf / Ff, f = bf % Ff;
  int tid = threadIdx.x;               // 0..511
  int group = tid >> 7;                // t-split quarter (2 waves)
  int half = (tid >> 6) & 1;           // l-split (wave-uniform)
  int lane = tid & 63;
  int d = lane & 7;                    // row channel
  int e = lane >> 3;                   // col channel

  // ---- stage Y into LDS
  if (!load_direct) {
    const float4* Yg = (const float4*)(Yt + (size_t)bf * (Cc * Tt));
    for (int i = tid; i < Cc * Tt / 2; i += 512) {
      float4 v = Yg[i];
      int c = i / (Tt / 2), t2 = (i % (Tt / 2)) * 2;
      *(float4*)&Yl[c][t2] = v;        // 16B aligned: 602*c + t2 even
    }
  } else {
    for (int i = tid; i < Cc * Tt; i += 512) {
      int c = i / Tt, t = i % Tt;
      size_t idx = (((size_t)b * Tt + t) * Cc + c) * Ff + f;
      Yl[c][t] = make_float2(in_re[idx], in_im[idx]);
    }
  }
  __syncthreads();

  const float2* Yd = &Yl[d][0];
  const float2* Ye = &Yl[e][0];

  int tA = (TQ * group) >> 2;
  int tB = (TQ * (group + 1)) >> 2;
  int si = tid >> 3;                   // solve row
  int sk = tid & 7;                    // solve col phase

  for (int iter = 0; iter < 3; ++iter) {
    // ---- weights (iter 0 from Y; iter 1 from enhanced_0); iter 2: store result
    if (iter == 0) {
      for (int t = tid; t < Tt; t += 512) {
        float s = 0.f;
#pragma unroll
        for (int c = 0; c < Cc; ++c) { float2 y = Yl[c][t]; s += y.x*y.x + y.y*y.y; }
        wl[t] = 1.0f / fmaxf(s * 0.125f, EPSF);
      }
    } else {
      for (int t = tid; t < Tt; t += 512) {
        float2 acc[Cc];
#pragma unroll
        for (int ee = 0; ee < Cc; ++ee) acc[ee] = Yl[ee][t];
        for (int p = 0; p < TAPS; ++p) {
          int ts = t - DELAY - p;
          if (ts < 0) break;   // zero-padded region
#pragma unroll
          for (int dd = 0; dd < Cc; ++dd) {
            float2 u = Yl[dd][ts];
            int j = p * Cc + dd;
#pragma unroll
            for (int ee = 0; ee < Cc; ++ee) {
              float2 g = RP[j][KC + ee];   // filter X[j][e] from the solve
              acc[ee].x -= g.x*u.x - g.y*u.y;
              acc[ee].y -= g.x*u.y + g.y*u.x;
            }
          }
        }
        if (iter == 1) {
          float s = 0.f;
#pragma unroll
          for (int ee = 0; ee < Cc; ++ee) s += acc[ee].x*acc[ee].x + acc[ee].y*acc[ee].y;
          wl[t] = 1.0f / fmaxf(s * 0.125f, EPSF);
        } else {
          if (!store_direct) {
            float2* Eg = enh + (size_t)bf * (Cc * Tt);
#pragma unroll
            for (int ee = 0; ee < Cc; ++ee) Eg[ee * Tt + t] = acc[ee];
          } else {
            int il = ilens[b];
            bool live = (t < il);
#pragma unroll
            for (int ee = 0; ee < Cc; ++ee) {
              float2 v = live ? acc[ee] : make_float2(0.f, 0.f);
              size_t idx = (((size_t)b * Tt + t) * Cc + ee) * Ff + f;
              out_re[idx] = v.x;
              out_im[idx] = v.y;
            }
          }
        }
      }
    }
    if (iter == 2) break;
    __syncthreads();

    // ---- zero RP (atomic-merge target)
    {
      float2* RPf = &RP[0][0];
      for (int i = tid; i < KC * RPW; i += 512) RPf[i] = make_float2(0.f, 0.f);
    }
    __syncthreads();

    // ---- accumulate [R | P]: shift-register row window, unroll 1 (liveness!)
    if (half == 0) {
      float2 rac[5][3];
#pragma unroll
      for (int k = 0; k < 5; ++k)
#pragma unroll
        for (int l = 0; l < 3; ++l) rac[k][l] = make_float2(0.f, 0.f);

      float2 wd0 = Yd[tA], wd1 = Yd[tA + 1], wd2 = Yd[tA + 2], wd3 = Yd[tA + 3];
#pragma unroll 1
      for (int t = tA; t < tB; ++t) {
        float w = wl[t + 7];
        float2 wd4 = Yd[t + 4];
        float2 c0 = Ye[t + 4], c1 = Ye[t + 3], c2 = Ye[t + 2];
        float2 s0 = make_float2(w * c0.x, w * c0.y);
        float2 s1 = make_float2(w * c1.x, w * c1.y);
        float2 s2 = make_float2(w * c2.x, w * c2.y);
        ROWH0(0, wd4); ROWH0(1, wd3); ROWH0(2, wd2); ROWH0(3, wd1); ROWH0(4, wd0);
        wd0 = wd1; wd1 = wd2; wd2 = wd3; wd3 = wd4;
      }
#pragma unroll
      for (int k = 0; k < 5; ++k)
#pragma unroll
        for (int l = 0; l < 3; ++l) {
          atomicAdd(&RP[k * 8 + d][l * 8 + e].x, rac[k][l].x);
          atomicAdd(&RP[k * 8 + d][l * 8 + e].y, rac[k][l].y);
        }
    } else {
      float2 rac[5][2], pac[5];
#pragma unroll
      for (int k = 0; k < 5; ++k) {
        rac[k][0] = make_float2(0.f, 0.f);
        rac[k][1] = make_float2(0.f, 0.f);
        pac[k]    = make_float2(0.f, 0.f);
      }

      float2 wd0 = Yd[tA], wd1 = Yd[tA + 1], wd2 = Yd[tA + 2], wd3 = Yd[tA + 3];
#pragma unroll 1
      for (int t = tA; t < tB; ++t) {
        float w = wl[t + 7];
        float2 wd4 = Yd[t + 4];
        float2 c3 = Ye[t + 1], c4 = Ye[t], cp = Ye[t + 7];
        float2 s3 = make_float2(w * c3.x, w * c3.y);
        float2 s4 = make_float2(w * c4.x, w * c4.y);
        float2 sp = make_float2(w * cp.x, w * cp.y);
        ROWH1(0, wd4); ROWH1(1, wd3); ROWH1(2, wd2); ROWH1(3, wd1); ROWH1(4, wd0);
        wd0 = wd1; wd1 = wd2; wd2 = wd3; wd3 = wd4;
      }
#pragma unroll
      for (int k = 0; k < 5; ++k) {
        atomicAdd(&RP[k * 8 + d][3 * 8 + e].x, rac[k][0].x);
        atomicAdd(&RP[k * 8 + d][3 * 8 + e].y, rac[k][0].y);
        atomicAdd(&RP[k * 8 + d][4 * 8 + e].x, rac[k][1].x);
        atomicAdd(&RP[k * 8 + d][4 * 8 + e].y, rac[k][1].y);
        atomicAdd(&RP[k * 8 + d][KC + e].x, pac[k].x);
        atomicAdd(&RP[k * 8 + d][KC + e].y, pac[k].y);
      }
    }
    if (tid < KC) atomicAdd(&RP[tid][tid].x, EPSF);   // regularize
    __syncthreads();

    // ---- Gauss-Jordan with deferred pivot scaling: one barrier per pivot.
    for (int j = 0; j < KC; ++j) {
      if (si < KC && si != j) {
        float2 pv = RP[j][j];
        float idn = 1.0f / (pv.x * pv.x + pv.y * pv.y);
        float2 ip = make_float2(pv.x * idn, -pv.y * idn);
        float2 lij = cmul2(RP[si][j], ip);
        for (int k = j + 1 + sk; k < NC; k += 8) {
          float2 s = cmul2(lij, RP[j][k]);
          RP[si][k].x -= s.x;
          RP[si][k].y -= s.y;
        }
      }
      __syncthreads();
    }
    if (tid < KC * Cc) {
      int j = tid >> 3, ee = tid & 7;
      float2 pv = RP[j][j];
      float idn = 1.0f / (pv.x * pv.x + pv.y * pv.y);
      float2 ip = make_float2(pv.x * idn, -pv.y * idn);
      RP[j][KC + ee] = cmul2(RP[j][KC + ee], ip);
    }
    __syncthreads();
  }
}

// (B,F,C,T) float2 -> masked (B,T,C,F) re/im planes
__global__ __launch_bounds__(256) void k_tout(const float2* __restrict__ enh,
                                              const int* __restrict__ ilens,
                                              float* __restrict__ out_re,
                                              float* __restrict__ out_im) {
  __shared__ float2 tile[32][33];
  int t0 = blockIdx.x * 32, f0 = blockIdx.y * 32;
  int b = blockIdx.z >> 3, c = blockIdx.z & 7;
  int tx = threadIdx.x & 31, ty = threadIdx.x >> 5;
#pragma unroll
  for (int ii = 0; ii < 4; ++ii) {
    int f = f0 + ty + 8 * ii, t = t0 + tx;
    if (f < Ff && t < Tt)
      tile[ty + 8 * ii][tx] = enh[(((size_t)b * Ff + f) * Cc + c) * Tt + t];
  }
  __syncthreads();
  int il = ilens[b];
#pragma unroll
  for (int ii = 0; ii < 4; ++ii) {
    int t = t0 + ty + 8 * ii, f = f0 + tx;
    if (t < Tt && f < Ff) {
      float2 v = tile[tx][ty + 8 * ii];
      if (t >= il) v = make_float2(0.f, 0.f);
      size_t idx = (((size_t)b * Tt + t) * Cc + c) * Ff + f;
      out_re[idx] = v.x;
      out_im[idx] = v.y;
    }
  }
}

extern "C" void kernel_launch(void* const* d_in, const int* in_sizes, int n_in,
                              void* d_out, int out_size, void* d_ws, size_t ws_size,
                              hipStream_t stream) {
  const float* in_re = (const float*)d_in[0];
  const float* in_im = (const float*)d_in[1];
  const int* ilens = (const int*)d_in[2];
  float* out_re = (float*)d_out;
  float* out_im = out_re + NTOT;

  size_t ybytes = (size_t)Bb * Ff * Cc * Tt * sizeof(float2);  // 78,950,400 B
  int have_yt  = ws_size >= ybytes;
  int have_enh = ws_size >= 2 * ybytes;
  float2* Yt  = (float2*)d_ws;
  float2* enh = (float2*)((char*)d_ws + ybytes);

  if (have_yt) {
    dim3 g((Ff + 31) / 32, (Tt + 31) / 32, Bb * Cc);
    k_tin<<<g, dim3(256), 0, stream>>>(in_re, in_im, Yt);
  }
  {
    dim3 g(Bb * Ff);
    k_wpe<<<g, dim3(512), 0, stream>>>(Yt, enh, in_re, in_im, ilens,
                                       out_re, out_im,
                                       have_yt ? 0 : 1, have_enh ? 0 : 1);
  }
  if (have_enh) {
    dim3 g((Tt + 31) / 32, (Ff + 31) / 32, Bb * Cc);
    k_tout<<<g, dim3(256), 0, stream>>>(enh, ilens, out_re, out_im);
  }
}